// Round 6
// baseline (209.518 us; speedup 1.0000x reference)
//
#include <hip/hip_runtime.h>
#include <hip/hip_bf16.h>
#include <hip/hip_fp8.h>
#include <stdint.h>

#define B_   64
#define L_   512
#define E_   256
#define P_   64
#define KOUT 512
#define KS_  3
#define H_   512
#define T_   53
#define CINW 2688           // conv_w inner: 896*3
#define LE   516            // embp rows/batch: L + 4 (2 zero each side)
#define LPP  514            // posp rows/batch: L + 2 (1 zero each side)
#define COMW 2048           // 1536 ent + 512 sent_h

// fp8 uniform scaling: data x64, weights x64, accumulator /4096
#define FP8_S    64.0f
#define DESCALE  (1.0f / 4096.0f)

// prep-kernel grid sections
#define SEC_CW    0
#define SEC_EMBP  512
#define SEC_POSP  (SEC_EMBP + (B_ * LE / 4))     // 512 + 8256 = 8768
#define SEC_ENT   (SEC_POSP + (B_ * LPP / 4))    // 8768 + 8224 = 16992
#define SEC_POOL  (SEC_ENT + 2 * B_)             // 16992 + 128 = 17120
#define SEC_END   (SEC_POOL + 32)                // 17152

typedef __attribute__((ext_vector_type(4))) float f32x4;
typedef __attribute__((ext_vector_type(4))) int   i32x4;
typedef __attribute__((ext_vector_type(8))) int   i32x8;

__device__ __forceinline__ unsigned enc_f(float x) {
    unsigned u = __float_as_uint(x);
    return (u & 0x80000000u) ? ~u : (u | 0x80000000u);
}
__device__ __forceinline__ float dec_f(unsigned e) {
    return __uint_as_float((e & 0x80000000u) ? (e & 0x7fffffffu) : ~e);
}
__device__ __forceinline__ unsigned char f8c(float x) {
    __hip_fp8_e4m3 t(x);            // OCP e4m3fn (gfx950) — NOT fnuz
    return t.__x;
}

__device__ __forceinline__ void cp16(const void* g, void* l) {
    __builtin_amdgcn_global_load_lds(
        (const __attribute__((address_space(1))) unsigned int*)g,
        (__attribute__((address_space(3))) unsigned int*)l,
        16, 0, 0);
}

// ---------------------------------------------------------------------------
// Fused prep: 5 independent jobs selected by blockIdx.x section.
// CW section also computes corr[b][which][n] in fp32 (replaces corr_k).
// (passed R2/R4/R5, absmax unchanged — verbatim from the 178.9 µs run)
__global__ void prep(const float* __restrict__ conv_w,
                     const int* __restrict__ context,
                     const int* __restrict__ sidx,
                     const int* __restrict__ oidx,
                     const int* __restrict__ sdis,
                     const int* __restrict__ odis,
                     const float* __restrict__ etab,
                     const float* __restrict__ ptab,
                     unsigned char* __restrict__ wce,     // fp8, x64
                     unsigned char* __restrict__ wcp,     // fp8, x64
                     unsigned char* __restrict__ embp,    // fp8, x64
                     unsigned char* __restrict__ posp,    // fp8, x64
                     float* __restrict__ corr,            // fp32 exact
                     float* __restrict__ com,
                     unsigned* __restrict__ pooled) {
    __shared__ float w[CINW];
    const int blk = blockIdx.x;
    const int tid = threadIdx.x;

    if (blk < SEC_EMBP) {
        // ---- combine_w: one block per output channel n ----
        int n = blk;
        const float* src = conv_w + (size_t)n * CINW;
        for (int i = tid; i < CINW; i += 256) w[i] = src[i];
        __syncthreads();
        for (int i = tid; i < 5 * E_; i += 256) {
            int d = i >> 8, c = i & 255;
            float s = 0.f;
#pragma unroll
            for (int tau = 0; tau <= 2; tau++) {
                int seg = d - tau;
                if (seg >= 0 && seg <= 2) s += w[(seg * 256 + c) * 3 + tau];
            }
            wce[((size_t)d * KOUT + n) * E_ + c] = f8c(s * FP8_S);
        }
        for (int i = tid; i < 3 * 128; i += 256) {
            int tau = i >> 7, p = i & 127;
            wcp[((size_t)tau * KOUT + n) * 128 + p] = f8c(w[(768 + p) * 3 + tau] * FP8_S);
        }
        // ---- corr (fp32-exact): pair p = (b, which); 2 threads per pair ----
        {
            int p   = tid >> 1, sub = tid & 1;
            int bb  = p >> 1, which = p & 1;
            int token = context[bb * L_ + (which ? L_ - 1 : 0)];
            const float4* er4 = (const float4*)(etab + (size_t)token * E_ + sub * 128);
            int A = which ? (sub * 384 + 2) : (1536 + sub * 384);
            float s = 0.f;
#pragma unroll 8
            for (int c4 = 0; c4 < 32; c4++) {
                float4 v = er4[c4];
                int c = c4 * 4;
                s += v.x * w[A + 3 * c]     + v.y * w[A + 3 * c + 3]
                   + v.z * w[A + 3 * c + 6] + v.w * w[A + 3 * c + 9];
            }
            s += __shfl_xor(s, 1, 64);
            if (sub == 0) corr[(bb * 2 + which) * KOUT + n] = s;
        }
    } else if (blk < SEC_POSP) {
        // ---- build_embp (fp8 x64) ----
        int row = (blk - SEC_EMBP) * 4 + (tid >> 6);
        int lane = tid & 63;
        int b = row / LE, r = row % LE;
        unsigned char* out = embp + (size_t)row * E_;
        if (r < 2 || r >= LE - 2) {
            *(uchar4*)(out + lane * 4) = (uchar4){0, 0, 0, 0};
            return;
        }
        int token = context[b * L_ + (r - 2)];
        float4 v = *(const float4*)(etab + (size_t)token * E_ + lane * 4);
        uchar4 pk;
        pk.x = f8c(v.x * FP8_S); pk.y = f8c(v.y * FP8_S);
        pk.z = f8c(v.z * FP8_S); pk.w = f8c(v.w * FP8_S);
        *(uchar4*)(out + lane * 4) = pk;
    } else if (blk < SEC_ENT) {
        // ---- build_posp (fp8 x64) ----
        int row = (blk - SEC_POSP) * 4 + (tid >> 6);
        int lane = tid & 63;
        int b = row / LPP, r = row % LPP;
        unsigned char* out = posp + (size_t)row * 128;
        if (r < 1 || r >= LPP - 1) {
            *(unsigned short*)(out + lane * 2) = 0;
            return;
        }
        int l = r - 1;
        int which = lane >> 5;
        int i2 = (lane & 31) * 2;
        int t = which ? odis[b * L_ + l] : sdis[b * L_ + l];
        float2 v = *(const float2*)(ptab + (size_t)t * P_ + i2);
        unsigned short pk = (unsigned short)f8c(v.x * FP8_S)
                          | ((unsigned short)f8c(v.y * FP8_S) << 8);
        *(unsigned short*)(out + which * 64 + i2) = pk;
    } else if (blk < SEC_POOL) {
        // ---- entity_feats (fp32 exact) ----
        int idx = blk - SEC_ENT;
        int b = idx >> 1, which = idx & 1;
        const int* sp = which ? oidx : sidx;
        int s = sp[b * 2 + 0], e = sp[b * 2 + 1];
        const int* ctx = context + b * L_;
        float* outb = com + (size_t)b * COMW + which * 768;
        int d = tid;
        float sum = 0.f;
        for (int x = s; x <= e; ++x) sum += etab[(size_t)ctx[x] * E_ + d];
        outb[d] = sum / (float)(e - s + 1);
        outb[256 + d] = etab[(size_t)ctx[s - 1] * E_ + d];
        float r = 0.f;
        if (e + 1 < L_) r = etab[(size_t)ctx[e + 1] * E_ + d];
        outb[512 + d] = r;
    } else {
        // ---- zero pooled (atomicMax baseline; enc of any real value > 0) ----
        int base = ((blk - SEC_POOL) * 256 + tid) * 4;
        *(uint4*)(pooled + base) = (uint4){0, 0, 0, 0};
    }
}

// ---------------------------------------------------------------------------
// R11 conv: B-operand in registers via ZERO-dynamic-indexing (rule #20-safe):
// eight NAMED i32x8 regs (bA0..3 / bB0..3), token-pasted LOADB/COMPUTE macros,
// and a pairwise tile loop so every reg-set and LDS-buffer choice is lexically
// static. A keeps the R6-proven path: cp16 staging, XOR slot swizzle, 2x16KB
// dbuf, counted vmcnt (8 B-loads + 4 A-cp16 = 12 in flight). This removes B's
// LDS writes AND ds_reads (~halves the LDS pipe, the measured bottleneck);
// B tiles (16 KB, reused by 256 blocks) come from L1/L2 instead.
__global__ void __launch_bounds__(256, 2)
conv_gemm_pool(const unsigned char* __restrict__ embp,
               const unsigned char* __restrict__ posp,
               const unsigned char* __restrict__ wce,
               const unsigned char* __restrict__ wcp,
               const float* __restrict__ corr,
               unsigned* __restrict__ pooled) {
    __shared__ unsigned char sA[2][128 * 128];    // 32 KB A double-buffer

    const int tid  = threadIdx.x;
    const int lane = tid & 63;
    const int wave = tid >> 6;
    const int mt = blockIdx.x;
    const int nt = blockIdx.y;
    const int b  = mt >> 2;
    const int l0 = (mt & 3) * 128;
    const int n0 = nt * 128;

    const int wr = (wave & 1) * 64;
    const int wc = (wave >> 1) * 64;
    const int m  = lane & 15;
    const int q  = lane >> 4;

    f32x4 acc[4][4];
#pragma unroll
    for (int i = 0; i < 4; i++)
#pragma unroll
        for (int j = 0; j < 4; j++) acc[i][j] = (f32x4){0.f, 0.f, 0.f, 0.f};

    const int srow = tid >> 3;                       // staging row in round
    const int ssw  = ((tid & 7) ^ (srow & 7)) << 4;  // swizzled source slot

    auto stageA = [&](unsigned char* dst, int t) {
        const char* A; int As;
        if (t < 10) {            // emb: 5 taps x 2 K-chunks of 128B
            int tap = t >> 1, kc = (t & 1) << 7;
            A  = (const char*)embp + ((size_t)(b * LE + l0 + tap) << 8) + kc;
            As = E_;
        } else {                 // pos: tiles 10-12
            int tap = t - 10;
            A  = (const char*)posp + ((size_t)(b * LPP + l0 + tap) << 7);
            As = 128;
        }
        char* d = (char*)dst + tid * 16;
#pragma unroll
        for (int rnd = 0; rnd < 4; rnd++) {          // 4 cp16 / thread
            int r = srow + rnd * 32;                 // (r&7)==(srow&7)
            cp16(A + r * As + ssw, d + rnd * 4096);
        }
    };

    auto bbase = [&](int t, int& Bs) -> const unsigned char* {
        if (t < 10) {
            int tap = t >> 1, kc = (t & 1) << 7;
            Bs = E_;
            return wce + ((size_t)(tap * KOUT + n0) << 8) + kc;
        }
        int tap = t - 10;
        Bs = 128;
        return wcp + ((size_t)(tap * KOUT + n0) << 7);
    };

    // Named register sets — NO arrays, NO runtime selects (rule #20).
    i32x8 bA0, bA1, bA2, bA3, bB0, bB1, bB2, bB3;

// 4 rows x 32B = 8 global_load_dwordx4 per LOADB
#define LOADB(S, tt) do {                                                     \
    int _bs; const unsigned char* _bb = bbase((tt), _bs);                     \
    b##S##0 = *(const i32x8*)(_bb + (size_t)(wc +  0 + m) * _bs + q * 32);    \
    b##S##1 = *(const i32x8*)(_bb + (size_t)(wc + 16 + m) * _bs + q * 32);    \
    b##S##2 = *(const i32x8*)(_bb + (size_t)(wc + 32 + m) * _bs + q * 32);    \
    b##S##3 = *(const i32x8*)(_bb + (size_t)(wc + 48 + m) * _bs + q * 32);    \
} while (0)

// A frag from LDS (swizzled slots), 16 MFMA; scale 0x7f = exactly 1.0
#define COMPUTE(BUF, S) do {                                                  \
    const unsigned char* _pA = &sA[BUF][0];                                   \
    _Pragma("unroll")                                                         \
    for (int i = 0; i < 4; i++) {                                             \
        int _row = wr + i * 16 + m;                                           \
        const unsigned char* _rp = _pA + _row * 128;                          \
        int _x = (_row & 7) << 4;                                             \
        i32x4 _lo = *(const i32x4*)(_rp + (((q << 1) << 4) ^ _x));            \
        i32x4 _hi = *(const i32x4*)(_rp + ((((q << 1) | 1) << 4) ^ _x));      \
        i32x8 _af = (i32x8){_lo[0], _lo[1], _lo[2], _lo[3],                   \
                            _hi[0], _hi[1], _hi[2], _hi[3]};                  \
        acc[i][0] = __builtin_amdgcn_mfma_scale_f32_16x16x128_f8f6f4(         \
            _af, b##S##0, acc[i][0], 0, 0, 0, 0x7f7f7f7f, 0, 0x7f7f7f7f);     \
        acc[i][1] = __builtin_amdgcn_mfma_scale_f32_16x16x128_f8f6f4(         \
            _af, b##S##1, acc[i][1], 0, 0, 0, 0x7f7f7f7f, 0, 0x7f7f7f7f);     \
        acc[i][2] = __builtin_amdgcn_mfma_scale_f32_16x16x128_f8f6f4(         \
            _af, b##S##2, acc[i][2], 0, 0, 0, 0x7f7f7f7f, 0, 0x7f7f7f7f);     \
        acc[i][3] = __builtin_amdgcn_mfma_scale_f32_16x16x128_f8f6f4(         \
            _af, b##S##3, acc[i][3], 0, 0, 0, 0x7f7f7f7f, 0, 0x7f7f7f7f);     \
    }                                                                         \
} while (0)

    // prologue: tile 0 -> set A + sA[0]
    LOADB(A, 0);
    stageA(sA[0], 0);
    asm volatile("s_waitcnt vmcnt(0)" ::: "memory");
    __builtin_amdgcn_s_barrier();

    // 13 tiles = 6 pairs + tail. Per phase: prefetch next (8 B-loads + 4
    // A-cp16 = 12 in flight), counted vmcnt(12) drains current tile only.
#pragma unroll 1
    for (int u = 0; u < 6; u++) {
        int te = 2 * u;
        // even phase: compute tile te (sA[0], set A), prefetch te+1 -> B/sA[1]
        LOADB(B, te + 1);
        stageA(sA[1], te + 1);
        asm volatile("s_waitcnt vmcnt(12)" ::: "memory");
        __builtin_amdgcn_s_barrier();          // A(te) visible to all waves
        __builtin_amdgcn_sched_barrier(0);
        COMPUTE(0, A);
        __builtin_amdgcn_sched_barrier(0);
        __builtin_amdgcn_s_barrier();          // A(te) consumed by all waves
        // odd phase: compute tile te+1 (sA[1], set B), prefetch te+2 -> A/sA[0]
        LOADB(A, te + 2);
        stageA(sA[0], te + 2);
        asm volatile("s_waitcnt vmcnt(12)" ::: "memory");
        __builtin_amdgcn_s_barrier();
        __builtin_amdgcn_sched_barrier(0);
        COMPUTE(1, B);
        __builtin_amdgcn_sched_barrier(0);
        __builtin_amdgcn_s_barrier();
    }
    // tail: tile 12 (sA[0], set A) — prefetched by the u=5 odd phase
    asm volatile("s_waitcnt vmcnt(0)" ::: "memory");
    __builtin_amdgcn_s_barrier();
    __builtin_amdgcn_sched_barrier(0);
    COMPUTE(0, A);

#undef LOADB
#undef COMPUTE

    const float* corrb = corr + b * 2 * KOUT;
#pragma unroll
    for (int j = 0; j < 4; j++) {
        int col = n0 + wc + j * 16 + m;
        float mx = -3.4e38f;
#pragma unroll
        for (int i = 0; i < 4; i++)
#pragma unroll
            for (int r = 0; r < 4; r++) {
                float v = acc[i][j][r] * DESCALE;
                int l = l0 + wr + i * 16 + q * 4 + r;
                if (l == 0)      v -= corrb[col];
                if (l == L_ - 1) v -= corrb[KOUT + col];
                mx = fmaxf(mx, v);
            }
        mx = fmaxf(mx, __shfl_xor(mx, 16, 64));
        mx = fmaxf(mx, __shfl_xor(mx, 32, 64));
        if (q == 0) atomicMax(&pooled[b * KOUT + col], enc_f(mx));
    }
}

// ---------------------------------------------------------------------------
// lin1/lin2: R1's proven pair (lin_fused regressed ~11 µs — TLP starvation).
__global__ void lin1_k(const unsigned* __restrict__ pooled,
                       const float* __restrict__ conv_b,
                       const float* __restrict__ lin1_w,
                       const float* __restrict__ lin1_b,
                       float* __restrict__ com) {
    int bid = blockIdx.x;
    int wave = threadIdx.x >> 6, lane = threadIdx.x & 63;
    int b = bid >> 7;
    int h = (bid & 127) * 4 + wave;
    const float* w = lin1_w + (size_t)h * KOUT;
    const unsigned* pb = pooled + b * KOUT;
    float s = 0.f;
#pragma unroll
    for (int i = 0; i < 8; i++) {
        int k = lane + 64 * i;
        s += (dec_f(pb[k]) + conv_b[k]) * w[k];
    }
#pragma unroll
    for (int off = 32; off > 0; off >>= 1) s += __shfl_down(s, off, 64);
    if (lane == 0) com[(size_t)b * COMW + 1536 + h] = tanhf(s + lin1_b[h]);
}

__global__ void lin2_k(const float* __restrict__ com,
                       const float* __restrict__ lin2_w,
                       const float* __restrict__ lin2_b,
                       float* __restrict__ out) {
    int b = blockIdx.x;
    int wave = threadIdx.x >> 6, lane = threadIdx.x & 63;
    int t = blockIdx.y * 4 + wave;
    if (t >= T_) return;
    const float* w = lin2_w + (size_t)t * COMW;
    const float* c = com + (size_t)b * COMW;
    float s = 0.f;
#pragma unroll
    for (int i = 0; i < 32; i++) {
        int k = lane + 64 * i;
        s += c[k] * w[k];
    }
#pragma unroll
    for (int off = 32; off > 0; off >>= 1) s += __shfl_down(s, off, 64);
    if (lane == 0) out[b * T_ + t] = s + lin2_b[t];
}

// ---------------------------------------------------------------------------
extern "C" void kernel_launch(void* const* d_in, const int* in_sizes, int n_in,
                              void* d_out, int out_size, void* d_ws, size_t ws_size,
                              hipStream_t stream) {
    const int*   context = (const int*)d_in[0];
    const int*   sidx    = (const int*)d_in[1];
    const int*   oidx    = (const int*)d_in[2];
    const int*   sdis    = (const int*)d_in[3];
    const int*   odis    = (const int*)d_in[4];
    const float* etab    = (const float*)d_in[5];
    const float* ptab    = (const float*)d_in[6];
    const float* conv_w  = (const float*)d_in[7];
    const float* conv_b  = (const float*)d_in[8];
    const float* lin1_w  = (const float*)d_in[9];
    const float* lin1_b  = (const float*)d_in[10];
    const float* lin2_w  = (const float*)d_in[11];
    const float* lin2_b  = (const float*)d_in[12];
    float* out = (float*)d_out;

    char* ws = (char*)d_ws;
    size_t off = 0;
    unsigned char* embp = (unsigned char*)(ws + off);
    off += (size_t)B_ * LE * E_;                 // 8.45 MB (fp8)
    off = (off + 255) & ~(size_t)255;
    unsigned char* posp = (unsigned char*)(ws + off);
    off += (size_t)B_ * LPP * 128;               // 4.2 MB (fp8)
    off = (off + 255) & ~(size_t)255;
    unsigned char* wce = (unsigned char*)(ws + off);
    off += (size_t)5 * KOUT * E_;                // 655 KB (fp8)
    off = (off + 255) & ~(size_t)255;
    unsigned char* wcp = (unsigned char*)(ws + off);
    off += (size_t)3 * KOUT * 128;               // 197 KB (fp8)
    off = (off + 255) & ~(size_t)255;
    float* corr = (float*)(ws + off);
    off += (size_t)B_ * 2 * KOUT * 4;            // 256 KB
    off = (off + 255) & ~(size_t)255;
    unsigned* pooled = (unsigned*)(ws + off);
    off += (size_t)B_ * KOUT * 4;                // 128 KB
    off = (off + 255) & ~(size_t)255;
    float* com = (float*)(ws + off);
    off += (size_t)B_ * COMW * 4;                // 512 KB

    prep<<<dim3(SEC_END), dim3(256), 0, stream>>>(
        conv_w, context, sidx, oidx, sdis, odis, etab, ptab,
        wce, wcp, embp, posp, corr, com, pooled);
    conv_gemm_pool<<<dim3(256, 4), dim3(256), 0, stream>>>(embp, posp, wce, wcp, corr, pooled);
    lin1_k<<<dim3(8192), dim3(256), 0, stream>>>(pooled, conv_b, lin1_w, lin1_b, com);
    lin2_k<<<dim3(B_, 14), dim3(256), 0, stream>>>(com, lin2_w, lin2_b, out);
}

// Round 7
// 175.529 us; speedup vs baseline: 1.1936x; 1.1936x over previous
//
#include <hip/hip_runtime.h>
#include <hip/hip_bf16.h>
#include <hip/hip_fp8.h>
#include <stdint.h>

#define B_   64
#define L_   512
#define E_   256
#define P_   64
#define KOUT 512
#define KS_  3
#define H_   512
#define T_   53
#define CINW 2688           // conv_w inner: 896*3
#define LE   516            // embp rows/batch: L + 4 (2 zero each side)
#define LPP  514            // posp rows/batch: L + 2 (1 zero each side)
#define COMW 2048           // 1536 ent + 512 sent_h

// fp8 uniform scaling: data x64, weights x64, accumulator /4096
#define FP8_S    64.0f
#define DESCALE  (1.0f / 4096.0f)

// prep-kernel grid sections
#define SEC_CW    0
#define SEC_EMBP  512
#define SEC_POSP  (SEC_EMBP + (B_ * LE / 4))     // 512 + 8256 = 8768
#define SEC_ENT   (SEC_POSP + (B_ * LPP / 4))    // 8768 + 8224 = 16992
#define SEC_POOL  (SEC_ENT + 2 * B_)             // 16992 + 128 = 17120
#define SEC_END   (SEC_POOL + 32)                // 17152

typedef __attribute__((ext_vector_type(4))) float f32x4;
typedef __attribute__((ext_vector_type(4))) int   i32x4;
typedef __attribute__((ext_vector_type(8))) int   i32x8;

__device__ __forceinline__ unsigned enc_f(float x) {
    unsigned u = __float_as_uint(x);
    return (u & 0x80000000u) ? ~u : (u | 0x80000000u);
}
__device__ __forceinline__ float dec_f(unsigned e) {
    return __uint_as_float((e & 0x80000000u) ? (e & 0x7fffffffu) : ~e);
}
__device__ __forceinline__ unsigned char f8c(float x) {
    __hip_fp8_e4m3 t(x);            // OCP e4m3fn (gfx950) — NOT fnuz
    return t.__x;
}

__device__ __forceinline__ void cp16(const void* g, void* l) {
    __builtin_amdgcn_global_load_lds(
        (const __attribute__((address_space(1))) unsigned int*)g,
        (__attribute__((address_space(3))) unsigned int*)l,
        16, 0, 0);
}

// ---------------------------------------------------------------------------
// Fused prep: 5 independent jobs selected by blockIdx.x section.
// CW section also computes corr[b][which][n] in fp32 (replaces corr_k).
// (verbatim from the 178.9 µs run)
__global__ void prep(const float* __restrict__ conv_w,
                     const int* __restrict__ context,
                     const int* __restrict__ sidx,
                     const int* __restrict__ oidx,
                     const int* __restrict__ sdis,
                     const int* __restrict__ odis,
                     const float* __restrict__ etab,
                     const float* __restrict__ ptab,
                     unsigned char* __restrict__ wce,     // fp8, x64
                     unsigned char* __restrict__ wcp,     // fp8, x64
                     unsigned char* __restrict__ embp,    // fp8, x64
                     unsigned char* __restrict__ posp,    // fp8, x64
                     float* __restrict__ corr,            // fp32 exact
                     float* __restrict__ com,
                     unsigned* __restrict__ pooled) {
    __shared__ float w[CINW];
    const int blk = blockIdx.x;
    const int tid = threadIdx.x;

    if (blk < SEC_EMBP) {
        // ---- combine_w: one block per output channel n ----
        int n = blk;
        const float* src = conv_w + (size_t)n * CINW;
        for (int i = tid; i < CINW; i += 256) w[i] = src[i];
        __syncthreads();
        for (int i = tid; i < 5 * E_; i += 256) {
            int d = i >> 8, c = i & 255;
            float s = 0.f;
#pragma unroll
            for (int tau = 0; tau <= 2; tau++) {
                int seg = d - tau;
                if (seg >= 0 && seg <= 2) s += w[(seg * 256 + c) * 3 + tau];
            }
            wce[((size_t)d * KOUT + n) * E_ + c] = f8c(s * FP8_S);
        }
        for (int i = tid; i < 3 * 128; i += 256) {
            int tau = i >> 7, p = i & 127;
            wcp[((size_t)tau * KOUT + n) * 128 + p] = f8c(w[(768 + p) * 3 + tau] * FP8_S);
        }
        // ---- corr (fp32-exact): pair p = (b, which); 2 threads per pair ----
        {
            int p   = tid >> 1, sub = tid & 1;
            int bb  = p >> 1, which = p & 1;
            int token = context[bb * L_ + (which ? L_ - 1 : 0)];
            const float4* er4 = (const float4*)(etab + (size_t)token * E_ + sub * 128);
            int A = which ? (sub * 384 + 2) : (1536 + sub * 384);
            float s = 0.f;
#pragma unroll 8
            for (int c4 = 0; c4 < 32; c4++) {
                float4 v = er4[c4];
                int c = c4 * 4;
                s += v.x * w[A + 3 * c]     + v.y * w[A + 3 * c + 3]
                   + v.z * w[A + 3 * c + 6] + v.w * w[A + 3 * c + 9];
            }
            s += __shfl_xor(s, 1, 64);
            if (sub == 0) corr[(bb * 2 + which) * KOUT + n] = s;
        }
    } else if (blk < SEC_POSP) {
        // ---- build_embp (fp8 x64) ----
        int row = (blk - SEC_EMBP) * 4 + (tid >> 6);
        int lane = tid & 63;
        int b = row / LE, r = row % LE;
        unsigned char* out = embp + (size_t)row * E_;
        if (r < 2 || r >= LE - 2) {
            *(uchar4*)(out + lane * 4) = (uchar4){0, 0, 0, 0};
            return;
        }
        int token = context[b * L_ + (r - 2)];
        float4 v = *(const float4*)(etab + (size_t)token * E_ + lane * 4);
        uchar4 pk;
        pk.x = f8c(v.x * FP8_S); pk.y = f8c(v.y * FP8_S);
        pk.z = f8c(v.z * FP8_S); pk.w = f8c(v.w * FP8_S);
        *(uchar4*)(out + lane * 4) = pk;
    } else if (blk < SEC_ENT) {
        // ---- build_posp (fp8 x64) ----
        int row = (blk - SEC_POSP) * 4 + (tid >> 6);
        int lane = tid & 63;
        int b = row / LPP, r = row % LPP;
        unsigned char* out = posp + (size_t)row * 128;
        if (r < 1 || r >= LPP - 1) {
            *(unsigned short*)(out + lane * 2) = 0;
            return;
        }
        int l = r - 1;
        int which = lane >> 5;
        int i2 = (lane & 31) * 2;
        int t = which ? odis[b * L_ + l] : sdis[b * L_ + l];
        float2 v = *(const float2*)(ptab + (size_t)t * P_ + i2);
        unsigned short pk = (unsigned short)f8c(v.x * FP8_S)
                          | ((unsigned short)f8c(v.y * FP8_S) << 8);
        *(unsigned short*)(out + which * 64 + i2) = pk;
    } else if (blk < SEC_POOL) {
        // ---- entity_feats (fp32 exact) ----
        int idx = blk - SEC_ENT;
        int b = idx >> 1, which = idx & 1;
        const int* sp = which ? oidx : sidx;
        int s = sp[b * 2 + 0], e = sp[b * 2 + 1];
        const int* ctx = context + b * L_;
        float* outb = com + (size_t)b * COMW + which * 768;
        int d = tid;
        float sum = 0.f;
        for (int x = s; x <= e; ++x) sum += etab[(size_t)ctx[x] * E_ + d];
        outb[d] = sum / (float)(e - s + 1);
        outb[256 + d] = etab[(size_t)ctx[s - 1] * E_ + d];
        float r = 0.f;
        if (e + 1 < L_) r = etab[(size_t)ctx[e + 1] * E_ + d];
        outb[512 + d] = r;
    } else {
        // ---- zero pooled (atomicMax baseline; enc of any real value > 0) ----
        int base = ((blk - SEC_POOL) * 256 + tid) * 4;
        *(uint4*)(pooled + base) = (uint4){0, 0, 0, 0};
    }
}

// ---------------------------------------------------------------------------
// conv GEMM: VERBATIM the R6 kernel from the 178.9 µs run. LOCAL OPTIMUM —
// three restructure attempts all regressed:
//   R7  A-window staging:  +6 µs (vmcnt(0) drain bubbles at window seams)
//   R8  B-in-regs (array): +290 µs (rule #20: runtime select -> scratch)
//   R11 B-in-regs (named): +29 µs (B read 2x/block from L2 + latency exposed;
//        MfmaUtil 46->16 — global_load_lds' implicit overlap is the win)
// Do not restructure without the full 8-phase co-design.
__global__ void __launch_bounds__(256, 2)
conv_gemm_pool(const unsigned char* __restrict__ embp,
               const unsigned char* __restrict__ posp,
               const unsigned char* __restrict__ wce,
               const unsigned char* __restrict__ wcp,
               const float* __restrict__ corr,
               unsigned* __restrict__ pooled) {
    __shared__ unsigned char sT[2][2][128 * 128];

    const int tid  = threadIdx.x;
    const int lane = tid & 63;
    const int wave = tid >> 6;
    const int mt = blockIdx.x;
    const int nt = blockIdx.y;
    const int b  = mt >> 2;
    const int l0 = (mt & 3) * 128;
    const int n0 = nt * 128;

    const int wr = (wave & 1) * 64;
    const int wc = (wave >> 1) * 64;
    const int m  = lane & 15;
    const int q  = lane >> 4;

    f32x4 acc[4][4];
#pragma unroll
    for (int i = 0; i < 4; i++)
#pragma unroll
        for (int j = 0; j < 4; j++) acc[i][j] = (f32x4){0.f, 0.f, 0.f, 0.f};

    const int srow = tid >> 3;                       // row within round
    const int ssw  = ((tid & 7) ^ (srow & 7)) << 4;  // swizzled source slot

    auto bases = [&](int t, const char*& A, int& As, const char*& Bx, int& Bs) {
        if (t < 10) {            // emb phase: 5 taps x 2 K-chunks of 128B
            int tap = t >> 1, kc = (t & 1) << 7;
            A  = (const char*)embp + ((size_t)(b * LE + l0 + tap) << 8) + kc;
            As = E_;
            Bx = (const char*)wce + ((size_t)(tap * KOUT + n0) << 8) + kc;
            Bs = E_;
        } else {                 // pos phase: 3 taps x 1 chunk
            int tap = t - 10;
            A  = (const char*)posp + ((size_t)(b * LPP + l0 + tap) << 7);
            As = 128;
            Bx = (const char*)wcp + ((size_t)(tap * KOUT + n0) << 7);
            Bs = 128;
        }
    };

    auto stage = [&](int bf_, const char* A, int As, const char* Bx, int Bs) {
        char* dA = (char*)&sT[bf_][0][0] + tid * 16;
        char* dB = (char*)&sT[bf_][1][0] + tid * 16;
#pragma unroll
        for (int rnd = 0; rnd < 4; rnd++) {          // 8 global_load_lds / wave
            int r = srow + rnd * 32;                 // (r&7)==(srow&7)
            cp16(A  + r * As + ssw, dA + rnd * 4096);
            cp16(Bx + r * Bs + ssw, dB + rnd * 4096);
        }
    };

    auto frag = [&](const unsigned char* base, int row) -> i32x8 {
        const unsigned char* rp = base + row * 128;
        int x  = (row & 7) << 4;
        i32x4 lo = *(const i32x4*)(rp + (((q << 1) << 4) ^ x));
        i32x4 hi = *(const i32x4*)(rp + ((((q << 1) | 1) << 4) ^ x));
        return (i32x8){lo[0], lo[1], lo[2], lo[3], hi[0], hi[1], hi[2], hi[3]};
    };

    auto compute = [&](int bf_) {
        const unsigned char* pA = &sT[bf_][0][0];
        const unsigned char* pB = &sT[bf_][1][0];
        i32x8 af[4];
#pragma unroll
        for (int i = 0; i < 4; i++) af[i] = frag(pA, wr + i * 16 + m);
#pragma unroll
        for (int j = 0; j < 4; j++) {
            i32x8 bfv = frag(pB, wc + j * 16 + m);
#pragma unroll
            for (int i = 0; i < 4; i++)
                // scale bytes 0x7f (e8m0 bias 127) = exactly 1.0
                acc[i][j] = __builtin_amdgcn_mfma_scale_f32_16x16x128_f8f6f4(
                    af[i], bfv, acc[i][j], 0, 0, 0, 0x7f7f7f7f, 0, 0x7f7f7f7f);
        }
    };

    // 2-phase pipeline: 13 K=128 tiles
    {
        const char *A0, *B0; int As0, Bs0;
        bases(0, A0, As0, B0, Bs0);
        stage(0, A0, As0, B0, Bs0);
    }
    int cur = 0;
#pragma unroll 1
    for (int t = 0; t < 13; t++) {
        if (t < 12) {
            const char *A1, *B1; int As1, Bs1;
            bases(t + 1, A1, As1, B1, Bs1);
            stage(cur ^ 1, A1, As1, B1, Bs1);
            // wait only the 8 older loads (tile t); tile t+1's 8 stay in flight
            asm volatile("s_waitcnt vmcnt(8)" ::: "memory");
        } else {
            asm volatile("s_waitcnt vmcnt(0)" ::: "memory");
        }
        __builtin_amdgcn_s_barrier();          // tile t ready for all waves
        __builtin_amdgcn_sched_barrier(0);     // pin: no ds_read hoists above
        compute(cur);
        __builtin_amdgcn_sched_barrier(0);
        __builtin_amdgcn_s_barrier();          // tile t consumed by all waves
        cur ^= 1;
    }

    const float* corrb = corr + b * 2 * KOUT;
#pragma unroll
    for (int j = 0; j < 4; j++) {
        int col = n0 + wc + j * 16 + m;
        float mx = -3.4e38f;
#pragma unroll
        for (int i = 0; i < 4; i++)
#pragma unroll
            for (int r = 0; r < 4; r++) {
                float v = acc[i][j][r] * DESCALE;
                int l = l0 + wr + i * 16 + q * 4 + r;
                if (l == 0)      v -= corrb[col];
                if (l == L_ - 1) v -= corrb[KOUT + col];
                mx = fmaxf(mx, v);
            }
        mx = fmaxf(mx, __shfl_xor(mx, 16, 64));
        mx = fmaxf(mx, __shfl_xor(mx, 32, 64));
        if (q == 0) atomicMax(&pooled[b * KOUT + col], enc_f(mx));
    }
}

// ---------------------------------------------------------------------------
// lin1/lin2: R1's proven shapes, now with float4 (16B/lane) loads — same
// addresses/coalescing, 4x fewer VMEM instructions (G13).
__global__ void lin1_k(const unsigned* __restrict__ pooled,
                       const float* __restrict__ conv_b,
                       const float* __restrict__ lin1_w,
                       const float* __restrict__ lin1_b,
                       float* __restrict__ com) {
    int bid = blockIdx.x;
    int wave = threadIdx.x >> 6, lane = threadIdx.x & 63;
    int b = bid >> 7;
    int h = (bid & 127) * 4 + wave;
    const float* w = lin1_w + (size_t)h * KOUT;
    const unsigned* pb = pooled + b * KOUT;
    float s = 0.f;
#pragma unroll
    for (int i = 0; i < 2; i++) {
        int k = lane * 4 + i * 256;
        float4 w4 = *(const float4*)(w + k);
        uint4  p4 = *(const uint4*)(pb + k);
        float4 c4 = *(const float4*)(conv_b + k);
        s += (dec_f(p4.x) + c4.x) * w4.x + (dec_f(p4.y) + c4.y) * w4.y
           + (dec_f(p4.z) + c4.z) * w4.z + (dec_f(p4.w) + c4.w) * w4.w;
    }
#pragma unroll
    for (int off = 32; off > 0; off >>= 1) s += __shfl_down(s, off, 64);
    if (lane == 0) com[(size_t)b * COMW + 1536 + h] = tanhf(s + lin1_b[h]);
}

__global__ void lin2_k(const float* __restrict__ com,
                       const float* __restrict__ lin2_w,
                       const float* __restrict__ lin2_b,
                       float* __restrict__ out) {
    int b = blockIdx.x;
    int wave = threadIdx.x >> 6, lane = threadIdx.x & 63;
    int t = blockIdx.y * 4 + wave;
    if (t >= T_) return;
    const float* w = lin2_w + (size_t)t * COMW;
    const float* c = com + (size_t)b * COMW;
    float s = 0.f;
#pragma unroll
    for (int i = 0; i < 8; i++) {
        int k = lane * 4 + i * 256;
        float4 w4 = *(const float4*)(w + k);
        float4 c4 = *(const float4*)(c + k);
        s += c4.x * w4.x + c4.y * w4.y + c4.z * w4.z + c4.w * w4.w;
    }
#pragma unroll
    for (int off = 32; off > 0; off >>= 1) s += __shfl_down(s, off, 64);
    if (lane == 0) out[b * T_ + t] = s + lin2_b[t];
}

// ---------------------------------------------------------------------------
extern "C" void kernel_launch(void* const* d_in, const int* in_sizes, int n_in,
                              void* d_out, int out_size, void* d_ws, size_t ws_size,
                              hipStream_t stream) {
    const int*   context = (const int*)d_in[0];
    const int*   sidx    = (const int*)d_in[1];
    const int*   oidx    = (const int*)d_in[2];
    const int*   sdis    = (const int*)d_in[3];
    const int*   odis    = (const int*)d_in[4];
    const float* etab    = (const float*)d_in[5];
    const float* ptab    = (const float*)d_in[6];
    const float* conv_w  = (const float*)d_in[7];
    const float* conv_b  = (const float*)d_in[8];
    const float* lin1_w  = (const float*)d_in[9];
    const float* lin1_b  = (const float*)d_in[10];
    const float* lin2_w  = (const float*)d_in[11];
    const float* lin2_b  = (const float*)d_in[12];
    float* out = (float*)d_out;

    char* ws = (char*)d_ws;
    size_t off = 0;
    unsigned char* embp = (unsigned char*)(ws + off);
    off += (size_t)B_ * LE * E_;                 // 8.45 MB (fp8)
    off = (off + 255) & ~(size_t)255;
    unsigned char* posp = (unsigned char*)(ws + off);
    off += (size_t)B_ * LPP * 128;               // 4.2 MB (fp8)
    off = (off + 255) & ~(size_t)255;
    unsigned char* wce = (unsigned char*)(ws + off);
    off += (size_t)5 * KOUT * E_;                // 655 KB (fp8)
    off = (off + 255) & ~(size_t)255;
    unsigned char* wcp = (unsigned char*)(ws + off);
    off += (size_t)3 * KOUT * 128;               // 197 KB (fp8)
    off = (off + 255) & ~(size_t)255;
    float* corr = (float*)(ws + off);
    off += (size_t)B_ * 2 * KOUT * 4;            // 256 KB
    off = (off + 255) & ~(size_t)255;
    unsigned* pooled = (unsigned*)(ws + off);
    off += (size_t)B_ * KOUT * 4;                // 128 KB
    off = (off + 255) & ~(size_t)255;
    float* com = (float*)(ws + off);
    off += (size_t)B_ * COMW * 4;                // 512 KB

    prep<<<dim3(SEC_END), dim3(256), 0, stream>>>(
        conv_w, context, sidx, oidx, sdis, odis, etab, ptab,
        wce, wcp, embp, posp, corr, com, pooled);
    conv_gemm_pool<<<dim3(256, 4), dim3(256), 0, stream>>>(embp, posp, wce, wcp, corr, pooled);
    lin1_k<<<dim3(8192), dim3(256), 0, stream>>>(pooled, conv_b, lin1_w, lin1_b, com);
    lin2_k<<<dim3(B_, 14), dim3(256), 0, stream>>>(com, lin2_w, lin2_b, out);
}